// Round 21
// baseline (116.016 us; speedup 1.0000x reference)
//
#include <hip/hip_runtime.h>

typedef __bf16 bf16;
typedef __bf16 bf16x4 __attribute__((ext_vector_type(4)));
typedef __bf16 bf16x8 __attribute__((ext_vector_type(8)));
typedef float  f32x4  __attribute__((ext_vector_type(4)));

#define T_SEQ  2048
#define NHEAD  16
#define DHEAD  64
#define DMODEL 1024
#define MTOT   4096  // B*T
#define L2E    1.4426950408889634f

static __device__ __forceinline__ f32x4 mfma16(bf16x8 a, bf16x8 b, f32x4 c) {
    return __builtin_amdgcn_mfma_f32_16x16x32_bf16(a, b, c, 0, 0, 0);
}

// ---------------------------------------------------------------------------
// prep: weight transposes only (unchanged from round 20).
// ---------------------------------------------------------------------------
__global__ __launch_bounds__(256) void prep(
    const float* __restrict__ Wq, const float* __restrict__ Wk,
    const float* __restrict__ Wv, bf16* __restrict__ wt,
    const float* __restrict__ Wo, bf16* __restrict__ wot)
{
    __shared__ float t[64][68];
    const int bid = blockIdx.x, tid = threadIdx.x;

    const float* in; bf16* out;
    int R, Cc; long ib, ob; int r0, c0;
    if (bid < 768) {
        int w = bid >> 8, rem = bid & 255;
        int rt = rem & 15, head = rem >> 4;
        in  = (w == 0 ? Wq : w == 1 ? Wk : Wv);
        out = wt + (size_t)w * 1024 * 1024;
        R = 1024; Cc = 64;
        ib = (long)head * 65536; ob = (long)head * 65536;
        r0 = rt * 64; c0 = 0;
    } else {
        int b3 = bid - 768;
        in = Wo; out = wot;
        R = 1024; Cc = 1024;
        ib = 0; ob = 0;
        r0 = (b3 & 15) * 64; c0 = (b3 >> 4) * 64;
    }

#pragma unroll
    for (int i = 0; i < 4; ++i) {
        int idx = i * 256 + tid;
        int row = idx >> 4, cb = (idx & 15) * 4;
        float4 v = *(const float4*)&in[ib + (long)(r0 + row) * Cc + c0 + cb];
        t[row][cb + 0] = v.x; t[row][cb + 1] = v.y;
        t[row][cb + 2] = v.z; t[row][cb + 3] = v.w;
    }
    __syncthreads();
#pragma unroll
    for (int i = 0; i < 2; ++i) {
        int idx = i * 256 + tid;
        int row = idx >> 3, cb = (idx & 7) * 8;
        bf16x8 v;
#pragma unroll
        for (int j = 0; j < 8; ++j) v[j] = (bf16)t[cb + j][row];
        *(bf16x8*)&out[ob + (long)(c0 + row) * R + r0 + cb] = v;
    }
}

// ---------------------------------------------------------------------------
// QKV projection with T14 register-prefetch pipeline, fp32-x direct read,
// permuted-t V store (unchanged from round 20).
// ---------------------------------------------------------------------------
__global__ __launch_bounds__(256) void qkv_gemm(
    const float* __restrict__ x, const bf16* __restrict__ wt,
    const float* __restrict__ bq, const float* __restrict__ bk,
    const float* __restrict__ bv,
    bf16* __restrict__ qws, bf16* __restrict__ kws, bf16* __restrict__ vtws)
{
    __shared__ __align__(16) bf16 xs[128][72];
    __shared__ __align__(16) bf16 wsh[3][64][72];

    const int m0 = blockIdx.x * 128;
    const int h  = blockIdx.y;
    const int tid = threadIdx.x, wid = tid >> 6, lane = tid & 63;
    const int lr = lane & 15, lg = lane >> 4;

    const bf16* wbase[3];
#pragma unroll
    for (int w = 0; w < 3; ++w)
        wbase[w] = wt + ((size_t)(w * NHEAD + h)) * DHEAD * DMODEL;

    f32x4 acc[3][2][4];
#pragma unroll
    for (int w = 0; w < 3; ++w)
#pragma unroll
        for (int mi = 0; mi < 2; ++mi)
#pragma unroll
            for (int nt = 0; nt < 4; ++nt) acc[w][mi][nt] = (f32x4)0.0f;

    float4 xr[4][2];
    bf16x8 wr[3][2];
#pragma unroll
    for (int i = 0; i < 4; ++i) {
        int idx = i * 256 + tid;
        int row = idx >> 3, cb = (idx & 7) * 8;
        xr[i][0] = *(const float4*)&x[(size_t)(m0 + row) * DMODEL + cb];
        xr[i][1] = *(const float4*)&x[(size_t)(m0 + row) * DMODEL + cb + 4];
    }
#pragma unroll
    for (int w = 0; w < 3; ++w)
#pragma unroll
        for (int i = 0; i < 2; ++i) {
            int idx = i * 256 + tid;
            int row = idx >> 3, cb = (idx & 7) * 8;
            wr[w][i] = *(const bf16x8*)&wbase[w][(size_t)row * DMODEL + cb];
        }

    for (int kt = 0; kt < 16; ++kt) {
        __syncthreads();
#pragma unroll
        for (int i = 0; i < 4; ++i) {
            int idx = i * 256 + tid;
            int row = idx >> 3, cb = (idx & 7) * 8;
            bf16x8 v;
            v[0] = (bf16)xr[i][0].x; v[1] = (bf16)xr[i][0].y;
            v[2] = (bf16)xr[i][0].z; v[3] = (bf16)xr[i][0].w;
            v[4] = (bf16)xr[i][1].x; v[5] = (bf16)xr[i][1].y;
            v[6] = (bf16)xr[i][1].z; v[7] = (bf16)xr[i][1].w;
            *(bf16x8*)&xs[row][cb] = v;
        }
#pragma unroll
        for (int w = 0; w < 3; ++w)
#pragma unroll
            for (int i = 0; i < 2; ++i) {
                int idx = i * 256 + tid;
                int row = idx >> 3, cb = (idx & 7) * 8;
                *(bf16x8*)&wsh[w][row][cb] = wr[w][i];
            }
        __syncthreads();

        if (kt < 15) {
            const int kofs = (kt + 1) * 64;
#pragma unroll
            for (int i = 0; i < 4; ++i) {
                int idx = i * 256 + tid;
                int row = idx >> 3, cb = (idx & 7) * 8;
                xr[i][0] = *(const float4*)&x[(size_t)(m0 + row) * DMODEL + kofs + cb];
                xr[i][1] = *(const float4*)&x[(size_t)(m0 + row) * DMODEL + kofs + cb + 4];
            }
#pragma unroll
            for (int w = 0; w < 3; ++w)
#pragma unroll
                for (int i = 0; i < 2; ++i) {
                    int idx = i * 256 + tid;
                    int row = idx >> 3, cb = (idx & 7) * 8;
                    wr[w][i] = *(const bf16x8*)&wbase[w][(size_t)row * DMODEL + kofs + cb];
                }
        }

        bf16x8 af[2][2];
#pragma unroll
        for (int mi = 0; mi < 2; ++mi)
#pragma unroll
            for (int ks = 0; ks < 2; ++ks)
                af[mi][ks] = *(const bf16x8*)&xs[wid * 32 + mi * 16 + lr][ks * 32 + lg * 8];

#pragma unroll
        for (int w = 0; w < 3; ++w)
#pragma unroll
            for (int nt = 0; nt < 4; ++nt)
#pragma unroll
                for (int ks = 0; ks < 2; ++ks) {
                    bf16x8 bfr = *(const bf16x8*)&wsh[w][nt * 16 + lr][ks * 32 + lg * 8];
#pragma unroll
                    for (int mi = 0; mi < 2; ++mi)
                        acc[w][mi][nt] = mfma16(af[mi][ks], bfr, acc[w][mi][nt]);
                }
    }

    const float* bias[3] = { bq + h * DHEAD, bk + h * DHEAD, bv + h * DHEAD };
#pragma unroll
    for (int w = 0; w < 3; ++w)
#pragma unroll
        for (int nt = 0; nt < 4; ++nt) {
            int d = nt * 16 + lr;
            float bs = bias[w][d];
#pragma unroll
            for (int mi = 0; mi < 2; ++mi)
#pragma unroll
                for (int j = 0; j < 4; ++j) {
                    int mrow = m0 + wid * 32 + mi * 16 + lg * 4 + j;
                    int b = mrow >> 11, t = mrow & 2047;
                    float val = acc[w][mi][nt][j] + bs;
                    size_t bh = (size_t)b * NHEAD + h;
                    if (w == 0) {
                        qws[(bh * T_SEQ + t) * DHEAD + d] = (bf16)val;
                    } else if (w == 1) {
                        kws[(bh * T_SEQ + t) * DHEAD + d] = (bf16)val;
                    } else {
                        // permuted-t V store (bijective within each 64-tile)
                        int tc = t & 63;
                        int pc = 32 * (tc >> 5) + 8 * ((tc >> 2) & 3)
                               + 4 * ((tc >> 4) & 1) + (tc & 3);
                        vtws[(bh * DHEAD + d) * T_SEQ + (t & ~63) + pc] = (bf16)val;
                    }
                }
        }
}

// ---------------------------------------------------------------------------
// Fused flash attention, KV-split, 2 q-groups/wave, PERMUTED-V PV,
// MFMA ones-column row sums.
// Round-21: 128-row KV MACRO-TILES -- each barrier span covers two 64-row
// halves (proven inner code run twice), halving the barrier count (16 -> 8
// per block). LDS 72 KB (2 blocks/CU still); staging 4 b128/thread per
// macro-tile (same total bytes, half the issue points).
// ---------------------------------------------------------------------------
template<int S, bool PARTIAL>
__global__ __launch_bounds__(512, 4) void attn_split(
    const bf16* __restrict__ qws, const bf16* __restrict__ kws,
    const bf16* __restrict__ vtws,
    bf16* __restrict__ po, float* __restrict__ pml, bf16* __restrict__ aws)
{
    __shared__ __align__(16) bf16 kls[2][128][72];
    __shared__ __align__(16) bf16 vls[2][2][64][72];

    // XCD swizzle: total blocks = 256*S; per-XCD chunk = 32*S.
    const int id = blockIdx.x;
    const int w  = (id & 7) * (32 * S) + (id >> 3);
    const int bh = w / (8 * S);
    const int rem = w - bh * (8 * S);
    const int qt = rem / S;
    const int sidx = rem - qt * S;
    const int NT = 16 / S;                 // macro-tiles (128 rows) per split
    const int t0 = sidx * NT, t1 = t0 + NT;

    const int b = bh >> 4, h = bh & 15;
    const bf16* Q  = qws  + (size_t)bh * T_SEQ * DHEAD;
    const bf16* K  = kws  + (size_t)bh * T_SEQ * DHEAD;
    const bf16* Vt = vtws + (size_t)bh * DHEAD * T_SEQ;

    const int tid = threadIdx.x, wid = tid >> 6, lane = tid & 63;
    const int lr = lane & 15, lg = lane >> 4;

    // staging coords (512 threads): K rows srow, srow+64; V t-halves 0,1
    const int srow = tid >> 3, scb = (tid & 7) * 8;

    // ones fragment for the row-sum MFMA
    bf16x8 onesf;
#pragma unroll
    for (int j = 0; j < 8; ++j) onesf[j] = (bf16)1.0f;

    // Q fragments for both groups, pre-scaled by 1/sqrt(DMODEL) = 2^-5
    int q0[2];
    bf16x8 qf[2][2];
#pragma unroll
    for (int g = 0; g < 2; ++g) {
        q0[g] = qt * 256 + g * 128 + wid * 16;
#pragma unroll
        for (int ks = 0; ks < 2; ++ks) {
            bf16x8 v = *(const bf16x8*)&Q[(size_t)(q0[g] + lr) * DHEAD + ks * 32 + lg * 8];
#pragma unroll
            for (int j = 0; j < 8; ++j) v[j] = (bf16)((float)v[j] * 0.03125f);
            qf[g][ks] = v;
        }
    }

    f32x4 o[2][4], lsum[2];
#pragma unroll
    for (int g = 0; g < 2; ++g) {
#pragma unroll
        for (int nt = 0; nt < 4; ++nt) o[g][nt] = (f32x4)0.0f;
        lsum[g] = (f32x4)0.0f;
    }
    float mrun[2] = { -1e30f, -1e30f };
    float m2c[2]  = { -1e30f * L2E, -1e30f * L2E };   // cached mrun*L2E

    // prologue: stage macro-tile t0 into buf 0
    bf16x8 kr[2], vr[2];
    {
        int kvb = t0 * 128;
        kr[0] = *(const bf16x8*)&K[(size_t)(kvb + srow) * DHEAD + scb];
        kr[1] = *(const bf16x8*)&K[(size_t)(kvb + 64 + srow) * DHEAD + scb];
        vr[0] = *(const bf16x8*)&Vt[(size_t)srow * T_SEQ + kvb + scb];
        vr[1] = *(const bf16x8*)&Vt[(size_t)srow * T_SEQ + kvb + 64 + scb];
    }
    *(bf16x8*)&kls[0][srow][scb]      = kr[0];
    *(bf16x8*)&kls[0][64 + srow][scb] = kr[1];
    *(bf16x8*)&vls[0][0][srow][scb]   = vr[0];
    *(bf16x8*)&vls[0][1][srow][scb]   = vr[1];

    int cur = 0;
    for (int t = t0; t < t1; ++t) {
        __syncthreads();                 // buf[cur] visible to all waves

        const bool more = (t + 1) < t1;
        if (more) {
            int kvn = (t + 1) * 128;
            kr[0] = *(const bf16x8*)&K[(size_t)(kvn + srow) * DHEAD + scb];
            kr[1] = *(const bf16x8*)&K[(size_t)(kvn + 64 + srow) * DHEAD + scb];
            vr[0] = *(const bf16x8*)&Vt[(size_t)srow * T_SEQ + kvn + scb];
            vr[1] = *(const bf16x8*)&Vt[(size_t)srow * T_SEQ + kvn + 64 + scb];
        }

#pragma unroll
        for (int half = 0; half < 2; ++half) {
            // S^T for both groups: each k0/k1 read feeds 2 MFMAs
            f32x4 s[2][4];
            __builtin_amdgcn_s_setprio(1);
#pragma unroll
            for (int nt = 0; nt < 4; ++nt) {
                bf16x8 k0 = *(const bf16x8*)&kls[cur][half * 64 + nt * 16 + lr][0 + lg * 8];
                bf16x8 k1 = *(const bf16x8*)&kls[cur][half * 64 + nt * 16 + lr][32 + lg * 8];
#pragma unroll
                for (int g = 0; g < 2; ++g) {
                    s[g][nt] = mfma16(k0, qf[g][0], (f32x4)0.0f);
                    s[g][nt] = mfma16(k1, qf[g][1], s[g][nt]);
                }
            }
            __builtin_amdgcn_s_setprio(0);

            // softmax per group; pack P directly into the PV A-fragment
            bf16x8 pf[2][2];
#pragma unroll
            for (int g = 0; g < 2; ++g) {
                float vm0 = fmaxf(fmaxf(s[g][0][0], s[g][0][1]), fmaxf(s[g][0][2], s[g][0][3]));
                float vm1 = fmaxf(fmaxf(s[g][1][0], s[g][1][1]), fmaxf(s[g][1][2], s[g][1][3]));
                float vm2 = fmaxf(fmaxf(s[g][2][0], s[g][2][1]), fmaxf(s[g][2][2], s[g][2][3]));
                float vm3 = fmaxf(fmaxf(s[g][3][0], s[g][3][1]), fmaxf(s[g][3][2], s[g][3][3]));
                float vm = fmaxf(fmaxf(vm0, vm1), fmaxf(vm2, vm3));

                const bool skip = __all(vm <= mrun[g] + 8.0f);
                if (!skip) {
                    float vmr = fmaxf(vm, __shfl_xor(vm, 16));
                    vmr = fmaxf(vmr, __shfl_xor(vmr, 32));
                    float mnew = fmaxf(mrun[g], vmr);
                    float alpha = __builtin_amdgcn_exp2f((mrun[g] - mnew) * L2E);
                    mrun[g] = mnew;
                    m2c[g] = mnew * L2E;
                    float ab[4];
#pragma unroll
                    for (int j = 0; j < 4; ++j) ab[j] = __shfl(alpha, lg * 4 + j);
#pragma unroll
                    for (int j = 0; j < 4; ++j) lsum[g][j] *= ab[j];
#pragma unroll
                    for (int nt = 0; nt < 4; ++nt)
#pragma unroll
                        for (int j = 0; j < 4; ++j) o[g][nt][j] *= ab[j];
                }

                const float m2 = m2c[g];
                float p[4][4];
#pragma unroll
                for (int nt = 0; nt < 4; ++nt)
#pragma unroll
                    for (int j = 0; j < 4; ++j)
                        p[nt][j] = __builtin_amdgcn_exp2f(fmaf(s[g][nt][j], L2E, -m2));

#pragma unroll
                for (int ks = 0; ks < 2; ++ks) {
                    bf16x8 pk;
#pragma unroll
                    for (int j = 0; j < 4; ++j) {
                        pk[j]     = (bf16)p[2 * ks][j];
                        pk[j + 4] = (bf16)p[2 * ks + 1][j];
                    }
                    pf[g][ks] = pk;
                }
            }

            // O += P V (V pre-permuted); row sums via ones-column MFMA
            __builtin_amdgcn_s_setprio(1);
#pragma unroll
            for (int ks = 0; ks < 2; ++ks) {
#pragma unroll
                for (int g = 0; g < 2; ++g)
                    lsum[g] = mfma16(pf[g][ks], onesf, lsum[g]);
#pragma unroll
                for (int nt = 0; nt < 4; ++nt) {
                    bf16x8 vf = *(const bf16x8*)&vls[cur][half][nt * 16 + lr][ks * 32 + lg * 8];
#pragma unroll
                    for (int g = 0; g < 2; ++g)
                        o[g][nt] = mfma16(pf[g][ks], vf, o[g][nt]);
                }
            }
            __builtin_amdgcn_s_setprio(0);
        }

        if (more) {
            *(bf16x8*)&kls[cur ^ 1][srow][scb]      = kr[0];
            *(bf16x8*)&kls[cur ^ 1][64 + srow][scb] = kr[1];
            *(bf16x8*)&vls[cur ^ 1][0][srow][scb]   = vr[0];
            *(bf16x8*)&vls[cur ^ 1][1][srow][scb]   = vr[1];
        }
        cur ^= 1;
    }

    // epilogue per group: lsum[g][j] is the FULL row sum for q = q0+4*lg+j
#pragma unroll
    for (int g = 0; g < 2; ++g) {
        float linv[4];
#pragma unroll
        for (int j = 0; j < 4; ++j) linv[j] = 1.0f / lsum[g][j];

        if (PARTIAL) {
            const size_t pbase = (size_t)(sidx * 32 + bh) * T_SEQ * DHEAD;
#pragma unroll
            for (int nt = 0; nt < 4; ++nt) {
                int dcol = nt * 16 + lr;
#pragma unroll
                for (int j = 0; j < 4; ++j) {
                    int tq = q0[g] + lg * 4 + j;
                    po[pbase + (size_t)tq * DHEAD + dcol] = (bf16)(o[g][nt][j] * linv[j]);
                }
            }
            // pml needs (m, l) for q = q0+lr on lanes lg==0: select + shfl
            {
                int js = lr & 3;
                float wv = lsum[g][0];
                wv = (js == 1) ? lsum[g][1] : wv;
                wv = (js == 2) ? lsum[g][2] : wv;
                wv = (js == 3) ? lsum[g][3] : wv;
                float lrow_q = __shfl(wv, 16 * (lr >> 2) + (lr & 3));
                if (lg == 0) {
                    size_t mlidx = ((size_t)(sidx * 32 + bh) * T_SEQ + (q0[g] + lr)) * 2;
                    pml[mlidx]     = mrun[g];
                    pml[mlidx + 1] = lrow_q;
                }
            }
        } else {
            const size_t obase = ((size_t)b * T_SEQ) * DMODEL + (size_t)h * DHEAD;
#pragma unroll
            for (int nt = 0; nt < 4; ++nt) {
                int dcol = nt * 16 + lr;
#pragma unroll
                for (int j = 0; j < 4; ++j) {
                    int tq = q0[g] + lg * 4 + j;
                    aws[obase + (size_t)tq * DMODEL + dcol] = (bf16)(o[g][nt][j] * linv[j]);
                }
            }
        }
    }
}

// ---------------------------------------------------------------------------
// Combine S partial attention results (unchanged).
// ---------------------------------------------------------------------------
template<int S>
__global__ __launch_bounds__(256) void attn_combine(
    const bf16* __restrict__ po, const float* __restrict__ pml,
    bf16* __restrict__ aws)
{
    const int g = blockIdx.x * 256 + threadIdx.x;
    const int r = g >> 3, dblk = g & 7;
    const int bh = r >> 11, tq = r & 2047;

    float ms[S], ls[S];
    float m = -1e30f;
#pragma unroll
    for (int s = 0; s < S; ++s) {
        float2 v = ((const float2*)pml)[(size_t)(s * 32 + bh) * T_SEQ + tq];
        ms[s] = v.x; ls[s] = v.y;
        m = fmaxf(m, ms[s]);
    }
    float L = 0.f, wgt[S];
#pragma unroll
    for (int s = 0; s < S; ++s) {
        wgt[s] = ls[s] * __builtin_amdgcn_exp2f((ms[s] - m) * L2E);
        L += wgt[s];
    }
    float inv = 1.0f / L;

    float acc[8];
#pragma unroll
    for (int j = 0; j < 8; ++j) acc[j] = 0.f;
#pragma unroll
    for (int s = 0; s < S; ++s) {
        bf16x8 ov = *(const bf16x8*)&po[((size_t)(s * 32 + bh) * T_SEQ + tq) * DHEAD + dblk * 8];
        float c = wgt[s] * inv;
#pragma unroll
        for (int j = 0; j < 8; ++j) acc[j] = fmaf(c, (float)ov[j], acc[j]);
    }
    bf16x8 out;
#pragma unroll
    for (int j = 0; j < 8; ++j) out[j] = (bf16)acc[j];

    const int b = bh >> 4, h = bh & 15;
    *(bf16x8*)&aws[((size_t)(b * T_SEQ + tq)) * DMODEL + h * DHEAD + dblk * 8] = out;
}

// ---------------------------------------------------------------------------
// Output projection: 64x128 tiles, T14 prefetch (unchanged).
// ---------------------------------------------------------------------------
__global__ __launch_bounds__(256) void out_gemm(
    const bf16* __restrict__ a, const bf16* __restrict__ wot,
    const float* __restrict__ bo, float* __restrict__ out)
{
    __shared__ __align__(16) bf16 as[64][72];
    __shared__ __align__(16) bf16 wsh[128][72];

    const int m0 = blockIdx.x * 64, n0 = blockIdx.y * 128;
    const int tid = threadIdx.x, wid = tid >> 6, lane = tid & 63;
    const int lr = lane & 15, lg = lane >> 4;

    f32x4 acc[8];
#pragma unroll
    for (int nt = 0; nt < 8; ++nt) acc[nt] = (f32x4)0.0f;

    bf16x8 ar[2], wr[4];
#pragma unroll
    for (int i = 0; i < 2; ++i) {
        int idx = i * 256 + tid;
        int row = idx >> 3, cb = (idx & 7) * 8;
        ar[i] = *(const bf16x8*)&a[(size_t)(m0 + row) * DMODEL + cb];
    }
#pragma unroll
    for (int i = 0; i < 4; ++i) {
        int idx = i * 256 + tid;
        int row = idx >> 3, cb = (idx & 7) * 8;
        wr[i] = *(const bf16x8*)&wot[(size_t)(n0 + row) * DMODEL + cb];
    }

    for (int kt = 0; kt < 16; ++kt) {
        __syncthreads();
#pragma unroll
        for (int i = 0; i < 2; ++i) {
            int idx = i * 256 + tid;
            int row = idx >> 3, cb = (idx & 7) * 8;
            *(bf16x8*)&as[row][cb] = ar[i];
        }
#pragma unroll
        for (int i = 0; i < 4; ++i) {
            int idx = i * 256 + tid;
            int row = idx >> 3, cb = (idx & 7) * 8;
            *(bf16x8*)&wsh[row][cb] = wr[i];
        }
        __syncthreads();

        if (kt < 15) {
            const int kofs = (kt + 1) * 64;
#pragma unroll
            for (int i = 0; i < 2; ++i) {
                int idx = i * 256 + tid;
                int row = idx >> 3, cb = (idx & 7) * 8;
                ar[i] = *(const bf16x8*)&a[(size_t)(m0 + row) * DMODEL + kofs + cb];
            }
#pragma unroll
            for (int i = 0; i < 4; ++i) {
                int idx = i * 256 + tid;
                int row = idx >> 3, cb = (idx & 7) * 8;
                wr[i] = *(const bf16x8*)&wot[(size_t)(n0 + row) * DMODEL + kofs + cb];
            }
        }

        bf16x8 af[2];
#pragma unroll
        for (int ks = 0; ks < 2; ++ks)
            af[ks] = *(const bf16x8*)&as[wid * 16 + lr][ks * 32 + lg * 8];

#pragma unroll
        for (int nt = 0; nt < 8; ++nt)
#pragma unroll
            for (int ks = 0; ks < 2; ++ks) {
                bf16x8 bfr = *(const bf16x8*)&wsh[nt * 16 + lr][ks * 32 + lg * 8];
                acc[nt] = mfma16(af[ks], bfr, acc[nt]);
            }
    }

#pragma unroll
    for (int nt = 0; nt < 8; ++nt) {
        int n = n0 + nt * 16 + lr;
        float bs = bo[n];
#pragma unroll
        for (int j = 0; j < 4; ++j) {
            int m = m0 + wid * 16 + lg * 4 + j;
            out[(size_t)m * DMODEL + n] = acc[nt][j] + bs;
        }
    }
}

// ---------------------------------------------------------------------------
extern "C" void kernel_launch(void* const* d_in, const int* in_sizes, int n_in,
                              void* d_out, int out_size, void* d_ws, size_t ws_size,
                              hipStream_t stream)
{
    const float* x  = (const float*)d_in[0];
    const float* Wq = (const float*)d_in[1];
    const float* Wk = (const float*)d_in[2];
    const float* Wv = (const float*)d_in[3];
    const float* bq = (const float*)d_in[4];
    const float* bk = (const float*)d_in[5];
    const float* bv = (const float*)d_in[6];
    const float* Wo = (const float*)d_in[7];
    const float* bo = (const float*)d_in[8];
    float* out = (float*)d_out;

    const size_t M1 = (size_t)1024 * 1024;
    bf16* ws   = (bf16*)d_ws;
    bf16* aws  = ws;                 // 4M  [b,t,h*d] (combined attention out)
    bf16* qws  = ws + 4 * M1;        // 4M  [b,h,t,d]
    bf16* kws  = qws + 4 * M1;       // 4M  [b,h,t,d]
    bf16* vtws = kws + 4 * M1;       // 4M  [b,h,d,t] (t pre-permuted per 64-tile)
    bf16* wt   = vtws + 4 * M1;      // 3M  [3*h][d][c]
    bf16* wot  = wt + 3 * M1;        // 1M  [n][k]
    bf16* po   = wot + 1 * M1;       // S*4M bf16 partial O (normalized)

    const size_t BASE = 20 * M1 * 2;                        // 41.9 MB
    const size_t PER  = 4 * M1 * 2 + (size_t)65536 * 2 * 4; // 8.9 MB per split

    dim3 tb(256);
    prep<<<dim3(1024), tb, 0, stream>>>(Wq, Wk, Wv, wt, Wo, wot);
    qkv_gemm<<<dim3(MTOT / 128, NHEAD), tb, 0, stream>>>(x, wt, bq, bk, bv, qws, kws, vtws);

    if (ws_size >= BASE + 2 * PER) {
        // S=2: 512 blocks x 512 thr (proven best config)
        float* pml = (float*)(po + 2 * 4 * M1);
        attn_split<2, true><<<dim3(512), dim3(512), 0, stream>>>(qws, kws, vtws, po, pml, aws);
        attn_combine<2><<<dim3(2048), tb, 0, stream>>>(po, pml, aws);
    } else {
        attn_split<1, false><<<dim3(256), dim3(512), 0, stream>>>(qws, kws, vtws, po, nullptr, aws);
    }

    out_gemm<<<dim3(MTOT / 64, DMODEL / 128), tb, 0, stream>>>(aws, wot, bo, out);
}

// Round 22
// 114.315 us; speedup vs baseline: 1.0149x; 1.0149x over previous
//
#include <hip/hip_runtime.h>

typedef __bf16 bf16;
typedef __bf16 bf16x4 __attribute__((ext_vector_type(4)));
typedef __bf16 bf16x8 __attribute__((ext_vector_type(8)));
typedef float  f32x4  __attribute__((ext_vector_type(4)));

#define T_SEQ  2048
#define NHEAD  16
#define DHEAD  64
#define DMODEL 1024
#define MTOT   4096  // B*T
#define L2E    1.4426950408889634f

static __device__ __forceinline__ f32x4 mfma16(bf16x8 a, bf16x8 b, f32x4 c) {
    return __builtin_amdgcn_mfma_f32_16x16x32_bf16(a, b, c, 0, 0, 0);
}

// ---------------------------------------------------------------------------
// prep: weight transposes only.
//   blocks [0, 768)    : Wq/Wk/Wv transpose  [1024,64] -> [64,1024] bf16
//   blocks [768, 1024) : Wo transpose        [1024,1024] -> Wo^T bf16
// ---------------------------------------------------------------------------
__global__ __launch_bounds__(256) void prep(
    const float* __restrict__ Wq, const float* __restrict__ Wk,
    const float* __restrict__ Wv, bf16* __restrict__ wt,
    const float* __restrict__ Wo, bf16* __restrict__ wot)
{
    __shared__ float t[64][68];
    const int bid = blockIdx.x, tid = threadIdx.x;

    const float* in; bf16* out;
    int R, Cc; long ib, ob; int r0, c0;
    if (bid < 768) {
        int w = bid >> 8, rem = bid & 255;
        int rt = rem & 15, head = rem >> 4;
        in  = (w == 0 ? Wq : w == 1 ? Wk : Wv);
        out = wt + (size_t)w * 1024 * 1024;
        R = 1024; Cc = 64;
        ib = (long)head * 65536; ob = (long)head * 65536;
        r0 = rt * 64; c0 = 0;
    } else {
        int b3 = bid - 768;
        in = Wo; out = wot;
        R = 1024; Cc = 1024;
        ib = 0; ob = 0;
        r0 = (b3 & 15) * 64; c0 = (b3 >> 4) * 64;
    }

#pragma unroll
    for (int i = 0; i < 4; ++i) {
        int idx = i * 256 + tid;
        int row = idx >> 4, cb = (idx & 15) * 4;
        float4 v = *(const float4*)&in[ib + (long)(r0 + row) * Cc + c0 + cb];
        t[row][cb + 0] = v.x; t[row][cb + 1] = v.y;
        t[row][cb + 2] = v.z; t[row][cb + 3] = v.w;
    }
    __syncthreads();
#pragma unroll
    for (int i = 0; i < 2; ++i) {
        int idx = i * 256 + tid;
        int row = idx >> 3, cb = (idx & 7) * 8;
        bf16x8 v;
#pragma unroll
        for (int j = 0; j < 8; ++j) v[j] = (bf16)t[cb + j][row];
        *(bf16x8*)&out[ob + (long)(c0 + row) * R + r0 + cb] = v;
    }
}

// ---------------------------------------------------------------------------
// QKV projection with T14 register-prefetch pipeline; reads x as FP32
// directly (convert at ds_write); V stored with t pre-permuted per 64-tile.
// ---------------------------------------------------------------------------
__global__ __launch_bounds__(256) void qkv_gemm(
    const float* __restrict__ x, const bf16* __restrict__ wt,
    const float* __restrict__ bq, const float* __restrict__ bk,
    const float* __restrict__ bv,
    bf16* __restrict__ qws, bf16* __restrict__ kws, bf16* __restrict__ vtws)
{
    __shared__ __align__(16) bf16 xs[128][72];
    __shared__ __align__(16) bf16 wsh[3][64][72];

    const int m0 = blockIdx.x * 128;
    const int h  = blockIdx.y;
    const int tid = threadIdx.x, wid = tid >> 6, lane = tid & 63;
    const int lr = lane & 15, lg = lane >> 4;

    const bf16* wbase[3];
#pragma unroll
    for (int w = 0; w < 3; ++w)
        wbase[w] = wt + ((size_t)(w * NHEAD + h)) * DHEAD * DMODEL;

    f32x4 acc[3][2][4];
#pragma unroll
    for (int w = 0; w < 3; ++w)
#pragma unroll
        for (int mi = 0; mi < 2; ++mi)
#pragma unroll
            for (int nt = 0; nt < 4; ++nt) acc[w][mi][nt] = (f32x4)0.0f;

    float4 xr[4][2];
    bf16x8 wr[3][2];
#pragma unroll
    for (int i = 0; i < 4; ++i) {
        int idx = i * 256 + tid;
        int row = idx >> 3, cb = (idx & 7) * 8;
        xr[i][0] = *(const float4*)&x[(size_t)(m0 + row) * DMODEL + cb];
        xr[i][1] = *(const float4*)&x[(size_t)(m0 + row) * DMODEL + cb + 4];
    }
#pragma unroll
    for (int w = 0; w < 3; ++w)
#pragma unroll
        for (int i = 0; i < 2; ++i) {
            int idx = i * 256 + tid;
            int row = idx >> 3, cb = (idx & 7) * 8;
            wr[w][i] = *(const bf16x8*)&wbase[w][(size_t)row * DMODEL + cb];
        }

    for (int kt = 0; kt < 16; ++kt) {
        __syncthreads();
#pragma unroll
        for (int i = 0; i < 4; ++i) {
            int idx = i * 256 + tid;
            int row = idx >> 3, cb = (idx & 7) * 8;
            bf16x8 v;
            v[0] = (bf16)xr[i][0].x; v[1] = (bf16)xr[i][0].y;
            v[2] = (bf16)xr[i][0].z; v[3] = (bf16)xr[i][0].w;
            v[4] = (bf16)xr[i][1].x; v[5] = (bf16)xr[i][1].y;
            v[6] = (bf16)xr[i][1].z; v[7] = (bf16)xr[i][1].w;
            *(bf16x8*)&xs[row][cb] = v;
        }
#pragma unroll
        for (int w = 0; w < 3; ++w)
#pragma unroll
            for (int i = 0; i < 2; ++i) {
                int idx = i * 256 + tid;
                int row = idx >> 3, cb = (idx & 7) * 8;
                *(bf16x8*)&wsh[w][row][cb] = wr[w][i];
            }
        __syncthreads();

        if (kt < 15) {
            const int kofs = (kt + 1) * 64;
#pragma unroll
            for (int i = 0; i < 4; ++i) {
                int idx = i * 256 + tid;
                int row = idx >> 3, cb = (idx & 7) * 8;
                xr[i][0] = *(const float4*)&x[(size_t)(m0 + row) * DMODEL + kofs + cb];
                xr[i][1] = *(const float4*)&x[(size_t)(m0 + row) * DMODEL + kofs + cb + 4];
            }
#pragma unroll
            for (int w = 0; w < 3; ++w)
#pragma unroll
                for (int i = 0; i < 2; ++i) {
                    int idx = i * 256 + tid;
                    int row = idx >> 3, cb = (idx & 7) * 8;
                    wr[w][i] = *(const bf16x8*)&wbase[w][(size_t)row * DMODEL + kofs + cb];
                }
        }

        bf16x8 af[2][2];
#pragma unroll
        for (int mi = 0; mi < 2; ++mi)
#pragma unroll
            for (int ks = 0; ks < 2; ++ks)
                af[mi][ks] = *(const bf16x8*)&xs[wid * 32 + mi * 16 + lr][ks * 32 + lg * 8];

#pragma unroll
        for (int w = 0; w < 3; ++w)
#pragma unroll
            for (int nt = 0; nt < 4; ++nt)
#pragma unroll
                for (int ks = 0; ks < 2; ++ks) {
                    bf16x8 bfr = *(const bf16x8*)&wsh[w][nt * 16 + lr][ks * 32 + lg * 8];
#pragma unroll
                    for (int mi = 0; mi < 2; ++mi)
                        acc[w][mi][nt] = mfma16(af[mi][ks], bfr, acc[w][mi][nt]);
                }
    }

    const float* bias[3] = { bq + h * DHEAD, bk + h * DHEAD, bv + h * DHEAD };
#pragma unroll
    for (int w = 0; w < 3; ++w)
#pragma unroll
        for (int nt = 0; nt < 4; ++nt) {
            int d = nt * 16 + lr;
            float bs = bias[w][d];
#pragma unroll
            for (int mi = 0; mi < 2; ++mi)
#pragma unroll
                for (int j = 0; j < 4; ++j) {
                    int mrow = m0 + wid * 32 + mi * 16 + lg * 4 + j;
                    int b = mrow >> 11, t = mrow & 2047;
                    float val = acc[w][mi][nt][j] + bs;
                    size_t bh = (size_t)b * NHEAD + h;
                    if (w == 0) {
                        qws[(bh * T_SEQ + t) * DHEAD + d] = (bf16)val;
                    } else if (w == 1) {
                        kws[(bh * T_SEQ + t) * DHEAD + d] = (bf16)val;
                    } else {
                        // permuted-t V store (bijective within each 64-tile)
                        int tc = t & 63;
                        int pc = 32 * (tc >> 5) + 8 * ((tc >> 2) & 3)
                               + 4 * ((tc >> 4) & 1) + (tc & 3);
                        vtws[(bh * DHEAD + d) * T_SEQ + (t & ~63) + pc] = (bf16)val;
                    }
                }
        }
}

// ---------------------------------------------------------------------------
// Fused flash attention, KV-split, 2 q-groups/wave, PERMUTED-V PV,
// MFMA ones-column row sums (round-20 best configuration).
// ---------------------------------------------------------------------------
template<int S, bool PARTIAL>
__global__ __launch_bounds__(512, 4) void attn_split(
    const bf16* __restrict__ qws, const bf16* __restrict__ kws,
    const bf16* __restrict__ vtws,
    bf16* __restrict__ po, float* __restrict__ pml, bf16* __restrict__ aws)
{
    __shared__ __align__(16) bf16 kls[2][64][72];
    __shared__ __align__(16) bf16 vls[2][64][72];

    // XCD swizzle: total blocks = 256*S; per-XCD chunk = 32*S.
    const int id = blockIdx.x;
    const int w  = (id & 7) * (32 * S) + (id >> 3);
    const int bh = w / (8 * S);
    const int rem = w - bh * (8 * S);
    const int qt = rem / S;
    const int sidx = rem - qt * S;
    const int t0 = (sidx * 32) / S, t1 = ((sidx + 1) * 32) / S;

    const int b = bh >> 4, h = bh & 15;
    const bf16* Q  = qws  + (size_t)bh * T_SEQ * DHEAD;
    const bf16* K  = kws  + (size_t)bh * T_SEQ * DHEAD;
    const bf16* Vt = vtws + (size_t)bh * DHEAD * T_SEQ;

    const int tid = threadIdx.x, wid = tid >> 6, lane = tid & 63;
    const int lr = lane & 15, lg = lane >> 4;

    // staging coords: both K and V linear (V pre-permuted in global)
    const int srow = tid >> 3, scb = (tid & 7) * 8;

    // ones fragment for the row-sum MFMA
    bf16x8 onesf;
#pragma unroll
    for (int j = 0; j < 8; ++j) onesf[j] = (bf16)1.0f;

    // Q fragments for both groups, pre-scaled by 1/sqrt(DMODEL) = 2^-5
    int q0[2];
    bf16x8 qf[2][2];
#pragma unroll
    for (int g = 0; g < 2; ++g) {
        q0[g] = qt * 256 + g * 128 + wid * 16;
#pragma unroll
        for (int ks = 0; ks < 2; ++ks) {
            bf16x8 v = *(const bf16x8*)&Q[(size_t)(q0[g] + lr) * DHEAD + ks * 32 + lg * 8];
#pragma unroll
            for (int j = 0; j < 8; ++j) v[j] = (bf16)((float)v[j] * 0.03125f);
            qf[g][ks] = v;
        }
    }

    f32x4 o[2][4], lsum[2];
#pragma unroll
    for (int g = 0; g < 2; ++g) {
#pragma unroll
        for (int nt = 0; nt < 4; ++nt) o[g][nt] = (f32x4)0.0f;
        lsum[g] = (f32x4)0.0f;
    }
    float mrun[2] = { -1e30f, -1e30f };
    float m2c[2]  = { -1e30f * L2E, -1e30f * L2E };   // cached mrun*L2E

    // prologue: stage tile t0 into buf 0
    bf16x8 kr, vr;
    kr = *(const bf16x8*)&K[(size_t)(t0 * 64 + srow) * DHEAD + scb];
    vr = *(const bf16x8*)&Vt[(size_t)srow * T_SEQ + t0 * 64 + scb];
    *(bf16x8*)&kls[0][srow][scb] = kr;
    *(bf16x8*)&vls[0][srow][scb] = vr;

    int cur = 0;
    for (int t = t0; t < t1; ++t) {
        __syncthreads();                 // buf[cur] visible to all waves

        const bool more = (t + 1) < t1;
        if (more) {
            int kvn = (t + 1) * 64;
            kr = *(const bf16x8*)&K[(size_t)(kvn + srow) * DHEAD + scb];
            vr = *(const bf16x8*)&Vt[(size_t)srow * T_SEQ + kvn + scb];
        }

        // S^T for both groups: each k0/k1 read feeds 2 MFMAs
        f32x4 s[2][4];
        __builtin_amdgcn_s_setprio(1);
#pragma unroll
        for (int nt = 0; nt < 4; ++nt) {
            bf16x8 k0 = *(const bf16x8*)&kls[cur][nt * 16 + lr][0 + lg * 8];
            bf16x8 k1 = *(const bf16x8*)&kls[cur][nt * 16 + lr][32 + lg * 8];
#pragma unroll
            for (int g = 0; g < 2; ++g) {
                s[g][nt] = mfma16(k0, qf[g][0], (f32x4)0.0f);
                s[g][nt] = mfma16(k1, qf[g][1], s[g][nt]);
            }
        }
        __builtin_amdgcn_s_setprio(0);

        // softmax per group; pack P directly into the PV A-fragment
        bf16x8 pf[2][2];
#pragma unroll
        for (int g = 0; g < 2; ++g) {
            // per-lane max only; __all makes this equivalent to row-max test
            float vm0 = fmaxf(fmaxf(s[g][0][0], s[g][0][1]), fmaxf(s[g][0][2], s[g][0][3]));
            float vm1 = fmaxf(fmaxf(s[g][1][0], s[g][1][1]), fmaxf(s[g][1][2], s[g][1][3]));
            float vm2 = fmaxf(fmaxf(s[g][2][0], s[g][2][1]), fmaxf(s[g][2][2], s[g][2][3]));
            float vm3 = fmaxf(fmaxf(s[g][3][0], s[g][3][1]), fmaxf(s[g][3][2], s[g][3][3]));
            float vm = fmaxf(fmaxf(vm0, vm1), fmaxf(vm2, vm3));

            const bool skip = __all(vm <= mrun[g] + 8.0f);
            if (!skip) {
                // rare path: true row max via cross-lane reduce
                float vmr = fmaxf(vm, __shfl_xor(vm, 16));
                vmr = fmaxf(vmr, __shfl_xor(vmr, 32));
                float mnew = fmaxf(mrun[g], vmr);
                float alpha = __builtin_amdgcn_exp2f((mrun[g] - mnew) * L2E);
                mrun[g] = mnew;
                m2c[g] = mnew * L2E;
                float ab[4];
#pragma unroll
                for (int j = 0; j < 4; ++j) ab[j] = __shfl(alpha, lg * 4 + j);
#pragma unroll
                for (int j = 0; j < 4; ++j) lsum[g][j] *= ab[j];
#pragma unroll
                for (int nt = 0; nt < 4; ++nt)
#pragma unroll
                    for (int j = 0; j < 4; ++j) o[g][nt][j] *= ab[j];
            }

            const float m2 = m2c[g];
            float p[4][4];
#pragma unroll
            for (int nt = 0; nt < 4; ++nt)
#pragma unroll
                for (int j = 0; j < 4; ++j)
                    p[nt][j] = __builtin_amdgcn_exp2f(fmaf(s[g][nt][j], L2E, -m2));

            // pf[ks] = (p[2ks][0..3], p[2ks+1][0..3]) -- P stays in registers
#pragma unroll
            for (int ks = 0; ks < 2; ++ks) {
                bf16x8 pk;
#pragma unroll
                for (int j = 0; j < 4; ++j) {
                    pk[j]     = (bf16)p[2 * ks][j];
                    pk[j + 4] = (bf16)p[2 * ks + 1][j];
                }
                pf[g][ks] = pk;
            }
        }

        // O += P V (V pre-permuted); row sums via ones-column MFMA
        __builtin_amdgcn_s_setprio(1);
#pragma unroll
        for (int ks = 0; ks < 2; ++ks) {
#pragma unroll
            for (int g = 0; g < 2; ++g)
                lsum[g] = mfma16(pf[g][ks], onesf, lsum[g]);
#pragma unroll
            for (int nt = 0; nt < 4; ++nt) {
                bf16x8 vf = *(const bf16x8*)&vls[cur][nt * 16 + lr][ks * 32 + lg * 8];
#pragma unroll
                for (int g = 0; g < 2; ++g)
                    o[g][nt] = mfma16(pf[g][ks], vf, o[g][nt]);
            }
        }
        __builtin_amdgcn_s_setprio(0);

        if (more) {
            *(bf16x8*)&kls[cur ^ 1][srow][scb] = kr;
            *(bf16x8*)&vls[cur ^ 1][srow][scb] = vr;
        }
        cur ^= 1;
    }

    // epilogue per group: lsum[g][j] is the FULL row sum for q = q0+4*lg+j
#pragma unroll
    for (int g = 0; g < 2; ++g) {
        float linv[4];
#pragma unroll
        for (int j = 0; j < 4; ++j) linv[j] = 1.0f / lsum[g][j];

        if (PARTIAL) {
            const size_t pbase = (size_t)(sidx * 32 + bh) * T_SEQ * DHEAD;
#pragma unroll
            for (int nt = 0; nt < 4; ++nt) {
                int dcol = nt * 16 + lr;
#pragma unroll
                for (int j = 0; j < 4; ++j) {
                    int tq = q0[g] + lg * 4 + j;
                    po[pbase + (size_t)tq * DHEAD + dcol] = (bf16)(o[g][nt][j] * linv[j]);
                }
            }
            // pml needs (m, l) for q = q0+lr on lanes lg==0: select + shfl
            {
                int js = lr & 3;
                float wv = lsum[g][0];
                wv = (js == 1) ? lsum[g][1] : wv;
                wv = (js == 2) ? lsum[g][2] : wv;
                wv = (js == 3) ? lsum[g][3] : wv;
                float lrow_q = __shfl(wv, 16 * (lr >> 2) + (lr & 3));
                if (lg == 0) {
                    size_t mlidx = ((size_t)(sidx * 32 + bh) * T_SEQ + (q0[g] + lr)) * 2;
                    pml[mlidx]     = mrun[g];
                    pml[mlidx + 1] = lrow_q;
                }
            }
        } else {
            const size_t obase = ((size_t)b * T_SEQ) * DMODEL + (size_t)h * DHEAD;
#pragma unroll
            for (int nt = 0; nt < 4; ++nt) {
                int dcol = nt * 16 + lr;
#pragma unroll
                for (int j = 0; j < 4; ++j) {
                    int tq = q0[g] + lg * 4 + j;
                    aws[obase + (size_t)tq * DMODEL + dcol] = (bf16)(o[g][nt][j] * linv[j]);
                }
            }
        }
    }
}

// ---------------------------------------------------------------------------
// Combine S partial attention results.
// ---------------------------------------------------------------------------
template<int S>
__global__ __launch_bounds__(256) void attn_combine(
    const bf16* __restrict__ po, const float* __restrict__ pml,
    bf16* __restrict__ aws)
{
    const int g = blockIdx.x * 256 + threadIdx.x;
    const int r = g >> 3, dblk = g & 7;
    const int bh = r >> 11, tq = r & 2047;

    float ms[S], ls[S];
    float m = -1e30f;
#pragma unroll
    for (int s = 0; s < S; ++s) {
        float2 v = ((const float2*)pml)[(size_t)(s * 32 + bh) * T_SEQ + tq];
        ms[s] = v.x; ls[s] = v.y;
        m = fmaxf(m, ms[s]);
    }
    float L = 0.f, wgt[S];
#pragma unroll
    for (int s = 0; s < S; ++s) {
        wgt[s] = ls[s] * __builtin_amdgcn_exp2f((ms[s] - m) * L2E);
        L += wgt[s];
    }
    float inv = 1.0f / L;

    float acc[8];
#pragma unroll
    for (int j = 0; j < 8; ++j) acc[j] = 0.f;
#pragma unroll
    for (int s = 0; s < S; ++s) {
        bf16x8 ov = *(const bf16x8*)&po[((size_t)(s * 32 + bh) * T_SEQ + tq) * DHEAD + dblk * 8];
        float c = wgt[s] * inv;
#pragma unroll
        for (int j = 0; j < 8; ++j) acc[j] = fmaf(c, (float)ov[j], acc[j]);
    }
    bf16x8 out;
#pragma unroll
    for (int j = 0; j < 8; ++j) out[j] = (bf16)acc[j];

    const int b = bh >> 4, h = bh & 15;
    *(bf16x8*)&aws[((size_t)(b * T_SEQ + tq)) * DMODEL + h * DHEAD + dblk * 8] = out;
}

// ---------------------------------------------------------------------------
// Output projection: 64x128 tiles, T14 prefetch.
// ---------------------------------------------------------------------------
__global__ __launch_bounds__(256) void out_gemm(
    const bf16* __restrict__ a, const bf16* __restrict__ wot,
    const float* __restrict__ bo, float* __restrict__ out)
{
    __shared__ __align__(16) bf16 as[64][72];
    __shared__ __align__(16) bf16 wsh[128][72];

    const int m0 = blockIdx.x * 64, n0 = blockIdx.y * 128;
    const int tid = threadIdx.x, wid = tid >> 6, lane = tid & 63;
    const int lr = lane & 15, lg = lane >> 4;

    f32x4 acc[8];
#pragma unroll
    for (int nt = 0; nt < 8; ++nt) acc[nt] = (f32x4)0.0f;

    bf16x8 ar[2], wr[4];
#pragma unroll
    for (int i = 0; i < 2; ++i) {
        int idx = i * 256 + tid;
        int row = idx >> 3, cb = (idx & 7) * 8;
        ar[i] = *(const bf16x8*)&a[(size_t)(m0 + row) * DMODEL + cb];
    }
#pragma unroll
    for (int i = 0; i < 4; ++i) {
        int idx = i * 256 + tid;
        int row = idx >> 3, cb = (idx & 7) * 8;
        wr[i] = *(const bf16x8*)&wot[(size_t)(n0 + row) * DMODEL + cb];
    }

    for (int kt = 0; kt < 16; ++kt) {
        __syncthreads();
#pragma unroll
        for (int i = 0; i < 2; ++i) {
            int idx = i * 256 + tid;
            int row = idx >> 3, cb = (idx & 7) * 8;
            *(bf16x8*)&as[row][cb] = ar[i];
        }
#pragma unroll
        for (int i = 0; i < 4; ++i) {
            int idx = i * 256 + tid;
            int row = idx >> 3, cb = (idx & 7) * 8;
            *(bf16x8*)&wsh[row][cb] = wr[i];
        }
        __syncthreads();

        if (kt < 15) {
            const int kofs = (kt + 1) * 64;
#pragma unroll
            for (int i = 0; i < 2; ++i) {
                int idx = i * 256 + tid;
                int row = idx >> 3, cb = (idx & 7) * 8;
                ar[i] = *(const bf16x8*)&a[(size_t)(m0 + row) * DMODEL + kofs + cb];
            }
#pragma unroll
            for (int i = 0; i < 4; ++i) {
                int idx = i * 256 + tid;
                int row = idx >> 3, cb = (idx & 7) * 8;
                wr[i] = *(const bf16x8*)&wot[(size_t)(n0 + row) * DMODEL + kofs + cb];
            }
        }

        bf16x8 af[2];
#pragma unroll
        for (int ks = 0; ks < 2; ++ks)
            af[ks] = *(const bf16x8*)&as[wid * 16 + lr][ks * 32 + lg * 8];

#pragma unroll
        for (int nt = 0; nt < 8; ++nt)
#pragma unroll
            for (int ks = 0; ks < 2; ++ks) {
                bf16x8 bfr = *(const bf16x8*)&wsh[nt * 16 + lr][ks * 32 + lg * 8];
                acc[nt] = mfma16(af[ks], bfr, acc[nt]);
            }
    }

#pragma unroll
    for (int nt = 0; nt < 8; ++nt) {
        int n = n0 + nt * 16 + lr;
        float bs = bo[n];
#pragma unroll
        for (int j = 0; j < 4; ++j) {
            int m = m0 + wid * 16 + lg * 4 + j;
            out[(size_t)m * DMODEL + n] = acc[nt][j] + bs;
        }
    }
}

// ---------------------------------------------------------------------------
extern "C" void kernel_launch(void* const* d_in, const int* in_sizes, int n_in,
                              void* d_out, int out_size, void* d_ws, size_t ws_size,
                              hipStream_t stream)
{
    const float* x  = (const float*)d_in[0];
    const float* Wq = (const float*)d_in[1];
    const float* Wk = (const float*)d_in[2];
    const float* Wv = (const float*)d_in[3];
    const float* bq = (const float*)d_in[4];
    const float* bk = (const float*)d_in[5];
    const float* bv = (const float*)d_in[6];
    const float* Wo = (const float*)d_in[7];
    const float* bo = (const float*)d_in[8];
    float* out = (float*)d_out;

    const size_t M1 = (size_t)1024 * 1024;
    bf16* ws   = (bf16*)d_ws;
    bf16* aws  = ws;                 // 4M  [b,t,h*d] (combined attention out)
    bf16* qws  = ws + 4 * M1;        // 4M  [b,h,t,d]
    bf16* kws  = qws + 4 * M1;       // 4M  [b,h,t,d]
    bf16* vtws = kws + 4 * M1;       // 4M  [b,h,d,t] (t pre-permuted per 64-tile)
    bf16* wt   = vtws + 4 * M1;      // 3M  [3*h][d][c]
    bf16* wot  = wt + 3 * M1;        // 1M  [n][k]
    bf16* po   = wot + 1 * M1;       // S*4M bf16 partial O (normalized)

    const size_t BASE = 20 * M1 * 2;                        // 41.9 MB
    const size_t PER  = 4 * M1 * 2 + (size_t)65536 * 2 * 4; // 8.9 MB per split

    dim3 tb(256);
    prep<<<dim3(1024), tb, 0, stream>>>(Wq, Wk, Wv, wt, Wo, wot);
    qkv_gemm<<<dim3(MTOT / 128, NHEAD), tb, 0, stream>>>(x, wt, bq, bk, bv, qws, kws, vtws);

    if (ws_size >= BASE + 2 * PER) {
        // S=2: 512 blocks x 512 thr (proven best config)
        float* pml = (float*)(po + 2 * 4 * M1);
        attn_split<2, true><<<dim3(512), dim3(512), 0, stream>>>(qws, kws, vtws, po, pml, aws);
        attn_combine<2><<<dim3(2048), tb, 0, stream>>>(po, pml, aws);
    } else {
        attn_split<1, false><<<dim3(256), dim3(512), 0, stream>>>(qws, kws, vtws, po, nullptr, aws);
    }

    out_gemm<<<dim3(MTOT / 64, DMODEL / 128), tb, 0, stream>>>(aws, wot, bo, out);
}